// Round 7
// baseline (244.911 us; speedup 1.0000x reference)
//
#include <hip/hip_runtime.h>
#include <stdint.h>

// Per-row top-K magnitude masking, exact. x: (4096, 8192) fp32, K = 819.
// Exact radix select on the 31-bit abs pattern: 11 bits (2048 bins,
// u16-packed, 2 copies), 10 bits, 10 bits (u32, 1 copy).
//
// This rev: ROW IN LDS + global_load_lds STREAMING + RAW BARRIERS.
// R0-R6 forensics: the row was always register-resident (VGPR_Count showed
// arch VGPRs only; the buffer sat in AGPRs of the unified file) and every
// structure landed at 83-97 us because time = SUM of pipes (mem 6.3K + VALU
// 3.4K + DS 2K + slack ~ 12.5K cyc/row): phase-locked blocks alternate
// memory-burst / compute-burst CU-wide with zero overlap.
// Fix: double-buffered row in LDS. Next row streams in via fire-and-forget
// global_load_lds(width=16) UNDER the current row's phases; stores drain
// under the next row's phases (persistent block, 8 rows). All __syncthreads
// replaced by {s_waitcnt lgkmcnt(0); s_barrier} -- __syncthreads would
// drain vmcnt(0) at each of ~13 barriers/row and kill the prefetch overlap.
// Row boundaries wait with COUNTED vmcnt (16 steady / 8 tail): drains only
// the oldest 8 vmem ops (= next row's loads; loads+stores share vmcnt,
// retired in issue order), leaving this row's stores in flight.

constexpr int NCOLS = 8192;
constexpr int TPB   = 256;
constexpr int V4    = NCOLS / 4;   // 2048 uint4 per row
constexpr int VPT   = V4 / TPB;    // 8 uint4 per thread per pass
constexpr int RPB   = 8;           // rows per block (persistent loop); grid 512

constexpr int PAD = 8;             // words between histogram copies (bank shift)
constexpr int W1  = 1024;          // phase-1 words per copy (2048 bins, u16-packed)
constexpr int S1  = W1 + PAD;      // 1032
constexpr int C1  = 2;             // phase-1 copies (2 waves/copy)
constexpr int B2  = 1024;          // phase-2/3 bins (u32, single copy)
constexpr int S2  = B2 + PAD;      // 1032
constexpr int HW  = (C1 * S1 > S2) ? C1 * S1 : S2;   // 2064 words

struct Shared {
  uint32_t row[2][NCOLS];          // double-buffered row data: 64 KB
  uint32_t hist[HW];               // 8256 B
  uint32_t wavesum[4];
  uint32_t digit;
  uint32_t rem;
};                                  // ~73.9 KB -> 2 blocks/CU

// LDS-visibility barrier WITHOUT vmcnt drain (unlike __syncthreads).
__device__ __forceinline__ void lds_barrier() {
  asm volatile("s_waitcnt lgkmcnt(0)" ::: "memory");
  __builtin_amdgcn_s_barrier();
  asm volatile("" ::: "memory");
}

// Issue this wave's quarter of one row: 8 x global_load_lds (16 B/lane,
// 1024 B/instr), fire-and-forget (vmcnt-tracked, LDS dest linear).
__device__ __forceinline__ void prefetch_row(const uint32_t* __restrict__ gsrc,
                                             uint32_t* ldst, int wave, int lane) {
  const uint32_t* g = gsrc + wave * (NCOLS / 4) + lane * 4;
  uint32_t* l = ldst + wave * (NCOLS / 4);     // wave-uniform base
#pragma unroll
  for (int i = 0; i < 8; ++i) {
    __builtin_amdgcn_global_load_lds(
        (const __attribute__((address_space(1))) uint32_t*)(g + i * 256),
        (__attribute__((address_space(3))) uint32_t*)(l + i * 256),
        16, 0, 0);
  }
}

// Suffix-scan + winner pick. hb[] are this thread's bin counts over bins
// [tid*BPT, tid*BPT+BPT). S(b) = #candidates with digit >= b. Winner:
// S(b) >= rem && S(b+1) < rem (unique). Updates rem to rank within bin.
template <int BPT>
__device__ __forceinline__ uint32_t pick_winner(Shared& sh, const uint32_t (&hb)[BPT],
                                                uint32_t& rem, int tid, int lane, int wave) {
  uint32_t L = 0;
#pragma unroll
  for (int j = 0; j < BPT; ++j) L += hb[j];

  uint32_t suf = L;                        // wave inclusive suffix scan
#pragma unroll
  for (int off = 1; off < 64; off <<= 1) {
    uint32_t o = __shfl_down(suf, off, 64);
    suf += (lane + off < 64) ? o : 0u;
  }
  if (lane == 0) sh.wavesum[wave] = suf;
  lds_barrier();
  uint32_t addw = 0;
#pragma unroll
  for (int w = 0; w < 4; ++w) addw += (w > wave) ? sh.wavesum[w] : 0u;
  suf += addw;

  uint32_t s = suf - L;                    // S at bin (tid+1)*BPT
#pragma unroll
  for (int j = BPT - 1; j >= 0; --j) {
    uint32_t snext = s;
    s += hb[j];
    if (s >= rem && snext < rem) {
      sh.digit = (uint32_t)(tid * BPT + j);
      sh.rem = rem - snext;
    }
  }
  lds_barrier();
  uint32_t d = sh.digit;
  rem = sh.rem;
  // No trailing barrier: next phase's zero+barrier orders these reads
  // before any write to digit/rem/wavesum (zeroing touches hist[] only).
  return d;
}

// Phase 1: 11-bit digit (bits 30..20), 2048 bins, u16-packed, 2 copies.
// bin b -> word (b & 1023), halfword (b >> 10): the two halves differ by 128
// in the exponent field (never both hot); counts <= 4096 < 2^16.
__device__ __forceinline__ uint32_t phase1(Shared& sh, const uint4* __restrict__ rv,
                                           uint32_t& rem, int tid, int lane, int wave) {
  uint4* hz = (uint4*)sh.hist;
  constexpr int ZW4 = (C1 * S1) / 4;       // 516
  for (int i = tid; i < ZW4; i += TPB) hz[i] = make_uint4(0u, 0u, 0u, 0u);
  lds_barrier();

  uint32_t* h = &sh.hist[(wave >> 1) * S1];
#pragma unroll
  for (int i = 0; i < VPT; ++i) {
    uint4 t = rv[tid + i * TPB];           // conflict-free ds_read_b128
    uint32_t a[4] = {t.x, t.y, t.z, t.w};
#pragma unroll
    for (int j = 0; j < 4; ++j) {
      uint32_t d = (a[j] & 0x7fffffffu) >> 20;
      atomicAdd(&h[d & (W1 - 1)], 1u << ((d >> 10) << 4));
    }
  }
  lds_barrier();

  constexpr int BPT = 2048 / TPB;          // 8
  uint32_t hb[BPT];
#pragma unroll
  for (int j = 0; j < BPT; ++j) hb[j] = 0;
  const int wbase = (tid & 127) * BPT;
  const int shift = (tid >> 7) << 4;
#pragma unroll
  for (int c = 0; c < C1; ++c) {
    const uint4* hp = (const uint4*)&sh.hist[c * S1 + wbase];
#pragma unroll
    for (int q = 0; q < BPT / 4; ++q) {
      uint4 t = hp[q];
      hb[4 * q + 0] += (t.x >> shift) & 0xffffu;
      hb[4 * q + 1] += (t.y >> shift) & 0xffffu;
      hb[4 * q + 2] += (t.z >> shift) & 0xffffu;
      hb[4 * q + 3] += (t.w >> shift) & 0xffffu;
    }
  }
  return pick_winner<BPT>(sh, hb, rem, tid, lane, wave);
}

// Phases 2/3: 10-bit digit, 1024 u32 bins, single copy (few candidates).
__device__ __forceinline__ uint32_t phase23(Shared& sh, const uint4* __restrict__ rv,
                                            int dshift, int cshift, uint32_t cprefix,
                                            uint32_t& rem, int tid, int lane, int wave) {
  uint4* hz = (uint4*)sh.hist;
  constexpr int ZW4 = S2 / 4;              // 258
  for (int i = tid; i < ZW4; i += TPB) hz[i] = make_uint4(0u, 0u, 0u, 0u);
  lds_barrier();

#pragma unroll
  for (int i = 0; i < VPT; ++i) {
    uint4 t = rv[tid + i * TPB];
    uint32_t a[4] = {t.x, t.y, t.z, t.w};
#pragma unroll
    for (int j = 0; j < 4; ++j) {
      uint32_t key = a[j] & 0x7fffffffu;
      if ((key >> cshift) == cprefix)
        atomicAdd(&sh.hist[(key >> dshift) & (B2 - 1)], 1u);
    }
  }
  lds_barrier();

  constexpr int BPT = B2 / TPB;            // 4
  uint32_t hb[BPT];
  const uint4 t = *(const uint4*)&sh.hist[tid * BPT];
  hb[0] = t.x; hb[1] = t.y; hb[2] = t.z; hb[3] = t.w;
  return pick_winner<BPT>(sh, hb, rem, tid, lane, wave);
}

__global__ __launch_bounds__(TPB, 2) void topk_row_kernel(const float* __restrict__ x,
                                                          float* __restrict__ out,
                                                          int K, int nrows) {
  __shared__ Shared sh;
  const int tid  = threadIdx.x;
  const int lane = tid & 63;
  const int wave = tid >> 6;
  const int row0 = blockIdx.x * RPB;
  if (row0 >= nrows) return;
  const int R = (nrows - row0 < RPB) ? (nrows - row0) : RPB;

  const uint32_t* xg = (const uint32_t*)x + (size_t)row0 * NCOLS;
  uint32_t*       og = (uint32_t*)out + (size_t)row0 * NCOLS;

  // Prologue: rows 0 and 1 in flight; wait only row 0 (oldest 8 ops).
  prefetch_row(xg, sh.row[0], wave, lane);
  if (R > 1) {
    prefetch_row(xg + NCOLS, sh.row[1], wave, lane);
    asm volatile("s_waitcnt vmcnt(8)" ::: "memory");
  } else {
    asm volatile("s_waitcnt vmcnt(0)" ::: "memory");
  }
  __builtin_amdgcn_s_barrier();
  asm volatile("" ::: "memory");

  int cur = 0;
  for (int it = 0; it < R; ++it) {
    const uint4* rv = (const uint4*)sh.row[cur];

    uint32_t rem = (uint32_t)K;
    uint32_t d1 = phase1(sh, rv, rem, tid, lane, wave);
    uint32_t d2 = phase23(sh, rv, 10, 20, d1, rem, tid, lane, wave);
    uint32_t d3 = phase23(sh, rv, 0, 10, (d1 << 10) | d2, rem, tid, lane, wave);
    const uint32_t thr = (d1 << 20) | (d2 << 10) | d3;  // K-th largest |x| bits

    // Masked store: fire-and-forget (drains under next row's phases).
    uint4* outr = (uint4*)(og + (size_t)it * NCOLS);
#pragma unroll
    for (int i = 0; i < VPT; ++i) {
      uint4 o = rv[tid + i * TPB];
      o.x = ((o.x & 0x7fffffffu) >= thr) ? o.x : 0u;
      o.y = ((o.y & 0x7fffffffu) >= thr) ? o.y : 0u;
      o.z = ((o.z & 0x7fffffffu) >= thr) ? o.z : 0u;
      o.w = ((o.w & 0x7fffffffu) >= thr) ? o.w : 0u;
      outr[tid + i * TPB] = o;
    }

    lds_barrier();                         // all waves done reading row[cur]

    const bool pf = (it + 2 < R);
    if (pf) prefetch_row(xg + (size_t)(it + 2) * NCOLS, sh.row[cur], wave, lane);

    if (it + 1 < R) {
      // Outstanding (issue order): loads r+1 (8) [, stores r (8)] [, loads
      // r+2 (8)]. Counted wait retires exactly the oldest 8 = loads r+1.
      if (pf) asm volatile("s_waitcnt vmcnt(16)" ::: "memory");
      else    asm volatile("s_waitcnt vmcnt(8)"  ::: "memory");
      __builtin_amdgcn_s_barrier();
      asm volatile("" ::: "memory");
    }
    cur ^= 1;
  }
}

extern "C" void kernel_launch(void* const* d_in, const int* in_sizes, int n_in,
                              void* d_out, int out_size, void* d_ws, size_t ws_size,
                              hipStream_t stream) {
  (void)n_in; (void)out_size; (void)d_ws; (void)ws_size;
  const float* x = (const float*)d_in[0];
  float* out = (float*)d_out;
  const int rows = in_sizes[0] / NCOLS;
  const int K = (int)(0.1 * NCOLS + 0.5);  // round(819.2) = 819
  const int grid = (rows + RPB - 1) / RPB;
  topk_row_kernel<<<grid, TPB, 0, stream>>>(x, out, K, rows);
}

// Round 8
// 235.609 us; speedup vs baseline: 1.0395x; 1.0395x over previous
//
#include <hip/hip_runtime.h>
#include <stdint.h>

// Per-row top-K magnitude masking, exact. x: (4096, 8192) fp32, K = 819.
// Exact radix select on the 31-bit abs pattern: 11 bits (2048 bins,
// u16-packed, 2 copies/row), 10 bits, 10 bits (u32, 1 copy/row).
//
// This rev: PAIR-FUSED PHASES. Scoreboard R0-R7: seven structures (remat
// pins, wave-private no-barrier, LDS streaming + counted vmcnt) all land at
// 83-97 us; best is the simple block-per-row R1/R6 (83). No pipe ever
// exceeds ~30% -> the cost is the per-row chain of ~13 barrier-separated
// dependent stages (zero -> atomics -> combine -> scan -> pick, x3 phases),
// not any throughput limit. Lever: amortize the chain -- each block owns TWO
// consecutive rows and every phase pass serves both (same barriers, same
// scan windows, doubled independent atomic/VALU streams -> ILP inside each
// stage, halved per-row latency overhead, 64 KB contiguous memory bursts).
// Phase-1 contention dilution is preserved: 4 copies (2 per row), each copy
// still fed by 2 waves / 4096 atomics, u16-packed (halves differ by 128 in
// exponent -> never both hot; counts <= 4096 < 2^16).

constexpr int NCOLS = 8192;
constexpr int TPB   = 256;
constexpr int V4    = NCOLS / 4;   // 2048 uint4 per row
constexpr int VPT   = V4 / TPB;    // 8 uint4 per thread per row
constexpr int RPB   = 2;           // rows per block, phase-fused

constexpr int PAD = 8;             // words between histogram copies (bank shift)
constexpr int W1  = 1024;          // phase-1 words per copy (2048 bins, u16-packed)
constexpr int S1  = W1 + PAD;      // 1032
constexpr int B2  = 1024;          // phase-2/3 bins (u32, 1 copy per row)
constexpr int S2  = B2 + PAD;      // 1032
constexpr int HW  = 4 * S1;        // 4128 words (>= 2*S2): 16.5 KB

struct Shared {
  uint32_t hist[HW];               // ph1: copies [A0 A1 B0 B1]; ph2/3: [A B]
  uint32_t wavesumA[4], wavesumB[4];
  uint32_t digitA, remA, digitB, remB;
};

// Dual suffix-scan + winner pick, both rows in the same barrier windows.
// hb*[] = per-thread bin counts over bins [tid*BPT, tid*BPT+BPT).
// S(b) = #candidates with digit >= b; winner: S(b) >= rem > S(b+1) (unique).
template <int BPT>
__device__ __forceinline__ void pick_pair(Shared& sh,
                                          const uint32_t (&hbA)[BPT],
                                          const uint32_t (&hbB)[BPT],
                                          uint32_t& remA, uint32_t& remB,
                                          uint32_t& dA, uint32_t& dB,
                                          int tid, int lane, int wave) {
  uint32_t LA = 0, LB = 0;
#pragma unroll
  for (int j = 0; j < BPT; ++j) { LA += hbA[j]; LB += hbB[j]; }

  uint32_t sufA = LA, sufB = LB;           // wave inclusive suffix scans
#pragma unroll
  for (int off = 1; off < 64; off <<= 1) {
    uint32_t oA = __shfl_down(sufA, off, 64);
    uint32_t oB = __shfl_down(sufB, off, 64);
    sufA += (lane + off < 64) ? oA : 0u;
    sufB += (lane + off < 64) ? oB : 0u;
  }
  if (lane == 0) { sh.wavesumA[wave] = sufA; sh.wavesumB[wave] = sufB; }
  __syncthreads();
  uint32_t addwA = 0, addwB = 0;
#pragma unroll
  for (int w = 0; w < 4; ++w) {
    addwA += (w > wave) ? sh.wavesumA[w] : 0u;
    addwB += (w > wave) ? sh.wavesumB[w] : 0u;
  }
  sufA += addwA; sufB += addwB;

  uint32_t sA = sufA - LA;                 // S at bin (tid+1)*BPT, row A
#pragma unroll
  for (int j = BPT - 1; j >= 0; --j) {
    uint32_t snext = sA;
    sA += hbA[j];
    if (sA >= remA && snext < remA) {
      sh.digitA = (uint32_t)(tid * BPT + j);
      sh.remA = remA - snext;
    }
  }
  uint32_t sB = sufB - LB;                 // row B
#pragma unroll
  for (int j = BPT - 1; j >= 0; --j) {
    uint32_t snext = sB;
    sB += hbB[j];
    if (sB >= remB && snext < remB) {
      sh.digitB = (uint32_t)(tid * BPT + j);
      sh.remB = remB - snext;
    }
  }
  __syncthreads();
  dA = sh.digitA; remA = sh.remA;
  dB = sh.digitB; remB = sh.remB;
  // No trailing barrier: the next phase's zero+barrier orders these reads
  // before any write to digit/rem/wavesum (zeroing touches hist[] only).
}

// Phase 1 (pair): 11-bit digit (bits 30..20), 2048 bins, u16-packed,
// copies A:{0,1} B:{2,3}, wave w -> copy (w>>1).
__device__ __forceinline__ void phase1_pair(Shared& sh,
                                            const uint4 (&vA)[VPT],
                                            const uint4 (&vB)[VPT],
                                            uint32_t& remA, uint32_t& remB,
                                            uint32_t& d1A, uint32_t& d1B,
                                            int tid, int lane, int wave) {
  uint4* hz = (uint4*)sh.hist;
  constexpr int ZW4 = (4 * S1) / 4;        // 1032
  for (int i = tid; i < ZW4; i += TPB) hz[i] = make_uint4(0u, 0u, 0u, 0u);
  __syncthreads();

  uint32_t* hA = &sh.hist[(wave >> 1) * S1];
  uint32_t* hB = &sh.hist[(2 + (wave >> 1)) * S1];
#pragma unroll
  for (int i = 0; i < VPT; ++i) {
    uint32_t aA[4] = {vA[i].x, vA[i].y, vA[i].z, vA[i].w};
    uint32_t aB[4] = {vB[i].x, vB[i].y, vB[i].z, vB[i].w};
#pragma unroll
    for (int j = 0; j < 4; ++j) {
      uint32_t dA = (aA[j] & 0x7fffffffu) >> 20;
      uint32_t dB = (aB[j] & 0x7fffffffu) >> 20;
      atomicAdd(&hA[dA & (W1 - 1)], 1u << ((dA >> 10) << 4));
      atomicAdd(&hB[dB & (W1 - 1)], 1u << ((dB >> 10) << 4));
    }
  }
  __syncthreads();

  constexpr int BPT = 2048 / TPB;          // 8
  uint32_t hbA[BPT], hbB[BPT];
#pragma unroll
  for (int j = 0; j < BPT; ++j) { hbA[j] = 0; hbB[j] = 0; }
  const int wbase = (tid & 127) * BPT;
  const int shift = (tid >> 7) << 4;
#pragma unroll
  for (int c = 0; c < 2; ++c) {
    const uint4* hpA = (const uint4*)&sh.hist[c * S1 + wbase];
    const uint4* hpB = (const uint4*)&sh.hist[(2 + c) * S1 + wbase];
#pragma unroll
    for (int q = 0; q < BPT / 4; ++q) {
      uint4 tA = hpA[q], tB = hpB[q];
      hbA[4 * q + 0] += (tA.x >> shift) & 0xffffu;
      hbA[4 * q + 1] += (tA.y >> shift) & 0xffffu;
      hbA[4 * q + 2] += (tA.z >> shift) & 0xffffu;
      hbA[4 * q + 3] += (tA.w >> shift) & 0xffffu;
      hbB[4 * q + 0] += (tB.x >> shift) & 0xffffu;
      hbB[4 * q + 1] += (tB.y >> shift) & 0xffffu;
      hbB[4 * q + 2] += (tB.z >> shift) & 0xffffu;
      hbB[4 * q + 3] += (tB.w >> shift) & 0xffffu;
    }
  }
  pick_pair<BPT>(sh, hbA, hbB, remA, remB, d1A, d1B, tid, lane, wave);
}

// Phases 2/3 (pair): 10-bit digit, 1024 u32 bins, one copy per row
// (A at hist[0..], B at hist[S2..]); candidates only (~819/row).
__device__ __forceinline__ void phase23_pair(Shared& sh,
                                             const uint4 (&vA)[VPT],
                                             const uint4 (&vB)[VPT],
                                             int dshift, int cshift,
                                             uint32_t prefA, uint32_t prefB,
                                             uint32_t& remA, uint32_t& remB,
                                             uint32_t& dA, uint32_t& dB,
                                             int tid, int lane, int wave) {
  uint4* hz = (uint4*)sh.hist;
  constexpr int ZW4 = (2 * S2) / 4;        // 516
  for (int i = tid; i < ZW4; i += TPB) hz[i] = make_uint4(0u, 0u, 0u, 0u);
  __syncthreads();

#pragma unroll
  for (int i = 0; i < VPT; ++i) {
    uint32_t aA[4] = {vA[i].x, vA[i].y, vA[i].z, vA[i].w};
    uint32_t aB[4] = {vB[i].x, vB[i].y, vB[i].z, vB[i].w};
#pragma unroll
    for (int j = 0; j < 4; ++j) {
      uint32_t kA = aA[j] & 0x7fffffffu;
      uint32_t kB = aB[j] & 0x7fffffffu;
      if ((kA >> cshift) == prefA)
        atomicAdd(&sh.hist[(kA >> dshift) & (B2 - 1)], 1u);
      if ((kB >> cshift) == prefB)
        atomicAdd(&sh.hist[S2 + ((kB >> dshift) & (B2 - 1))], 1u);
    }
  }
  __syncthreads();

  constexpr int BPT = B2 / TPB;            // 4
  uint32_t hbA[BPT], hbB[BPT];
  const uint4 tA = *(const uint4*)&sh.hist[tid * BPT];
  const uint4 tB = *(const uint4*)&sh.hist[S2 + tid * BPT];
  hbA[0] = tA.x; hbA[1] = tA.y; hbA[2] = tA.z; hbA[3] = tA.w;
  hbB[0] = tB.x; hbB[1] = tB.y; hbB[2] = tB.z; hbB[3] = tB.w;
  pick_pair<BPT>(sh, hbA, hbB, remA, remB, dA, dB, tid, lane, wave);
}

__global__ __launch_bounds__(TPB, 4) void topk_row_kernel(const float* __restrict__ x,
                                                          float* __restrict__ out,
                                                          int K, int nrows) {
  __shared__ Shared sh;
  const int tid  = threadIdx.x;
  const int lane = tid & 63;
  const int wave = tid >> 6;
  const int rowA = blockIdx.x * RPB;
  const bool hasB = (rowA + 1 < nrows);

  const uint4* xrA = (const uint4*)(x) + (size_t)rowA * V4;
  const uint4* xrB = hasB ? (xrA + V4) : xrA;   // degenerate: duplicate row A

  uint4 vA[VPT], vB[VPT];
#pragma unroll
  for (int i = 0; i < VPT; ++i) { vA[i] = xrA[tid + i * TPB]; vB[i] = xrB[tid + i * TPB]; }
  // Pin both rows in the register file (forbids remat; parking in AGPRs is
  // fine -- proven cheap in R4-R6). Zero instructions.
#pragma unroll
  for (int i = 0; i < VPT; ++i) {
    asm volatile("" : "+v"(vA[i].x), "+v"(vA[i].y), "+v"(vA[i].z), "+v"(vA[i].w));
    asm volatile("" : "+v"(vB[i].x), "+v"(vB[i].y), "+v"(vB[i].z), "+v"(vB[i].w));
  }

  uint32_t remA = (uint32_t)K, remB = (uint32_t)K;
  uint32_t d1A, d1B, d2A, d2B, d3A, d3B;
  phase1_pair(sh, vA, vB, remA, remB, d1A, d1B, tid, lane, wave);
  phase23_pair(sh, vA, vB, 10, 20, d1A, d1B, remA, remB, d2A, d2B, tid, lane, wave);
  phase23_pair(sh, vA, vB, 0, 10, (d1A << 10) | d2A, (d1B << 10) | d2B,
               remA, remB, d3A, d3B, tid, lane, wave);

  const uint32_t thrA = (d1A << 20) | (d2A << 10) | d3A;  // K-th largest |x| bits
  const uint32_t thrB = (d1B << 20) | (d2B << 10) | d3B;

  uint4* outA = (uint4*)(out) + (size_t)rowA * V4;
#pragma unroll
  for (int i = 0; i < VPT; ++i) {
    uint4 o = vA[i];
    o.x = ((o.x & 0x7fffffffu) >= thrA) ? o.x : 0u;
    o.y = ((o.y & 0x7fffffffu) >= thrA) ? o.y : 0u;
    o.z = ((o.z & 0x7fffffffu) >= thrA) ? o.z : 0u;
    o.w = ((o.w & 0x7fffffffu) >= thrA) ? o.w : 0u;
    outA[tid + i * TPB] = o;
  }
  if (hasB) {
    uint4* outB = outA + V4;
#pragma unroll
    for (int i = 0; i < VPT; ++i) {
      uint4 o = vB[i];
      o.x = ((o.x & 0x7fffffffu) >= thrB) ? o.x : 0u;
      o.y = ((o.y & 0x7fffffffu) >= thrB) ? o.y : 0u;
      o.z = ((o.z & 0x7fffffffu) >= thrB) ? o.z : 0u;
      o.w = ((o.w & 0x7fffffffu) >= thrB) ? o.w : 0u;
      outB[tid + i * TPB] = o;
    }
  }
}

extern "C" void kernel_launch(void* const* d_in, const int* in_sizes, int n_in,
                              void* d_out, int out_size, void* d_ws, size_t ws_size,
                              hipStream_t stream) {
  (void)n_in; (void)out_size; (void)d_ws; (void)ws_size;
  const float* x = (const float*)d_in[0];
  float* out = (float*)d_out;
  const int rows = in_sizes[0] / NCOLS;
  const int K = (int)(0.1 * NCOLS + 0.5);  // round(819.2) = 819
  const int grid = (rows + RPB - 1) / RPB;
  topk_row_kernel<<<grid, TPB, 0, stream>>>(x, out, K, rows);
}

// Round 9
// 233.417 us; speedup vs baseline: 1.0492x; 1.0094x over previous
//
#include <hip/hip_runtime.h>
#include <stdint.h>

// Per-row top-K magnitude masking, exact.
// x: (4096 rows, 8192 cols) fp32. K = 819. One 256-thread block per row, row
// held in registers (8 x uint4 / thread). Exact radix select on the 31-bit
// abs bit pattern: phase 1 = 11 bits (2048 bins, u16-packed, 2 copies) over
// all 8192 elements; then COMPACT the winning bin (~200 elements for this
// distribution) into an LDS candidate list; phases 2/3 (10+10 bits, 1024
// u32 bins) run over the list only (<= 1 element/thread vs 32).
//
// Rationale (R0-R8 scoreboard): eight structures (occupancy 17-64%, zero
// barriers, streamed LDS rows with counted vmcnt, pair-fused phases,
// register pins) ALL land at 83-97 us -> the cost is the total per-row
// stage work, not scheduling. Phases 2/3 previously re-scanned all 8192
// elements (~45% of VALU + ~60 predicated wave-DS ops) to touch ~800/~80
// relevant ones. Only elements with 11-bit digit == d1 matter after phase 1
// (greater => surely kept, smaller => surely dropped; rem = rank within the
// d1 bin), so the list collapses phases 2/3 to noise. Exact for ANY input:
// list capped at 2048 with a uniform fallback to the full-scan path.

constexpr int NCOLS = 8192;
constexpr int TPB   = 256;
constexpr int V4    = NCOLS / 4;   // 2048 uint4 per row
constexpr int VPT   = V4 / TPB;    // 8 uint4 per thread

constexpr int PAD = 8;             // words between histogram copies (bank shift)
constexpr int W1  = 1024;          // phase-1 words per copy (2048 bins, u16-packed)
constexpr int S1  = W1 + PAD;      // 1032
constexpr int C1  = 2;             // phase-1 copies (2 waves/copy)
constexpr int B2  = 1024;          // phase-2/3 bins (u32, single copy)
constexpr int S2  = B2 + PAD;      // 1032
constexpr int HW  = (C1 * S1 > S2) ? C1 * S1 : S2;   // 2064 words

constexpr int CAND_MAX = 2048;     // d1-bin capacity (expected ~200 here)

struct Shared {
  uint32_t hist[HW];               // 8256 B
  uint32_t cand[CAND_MAX];         // 8 KB candidate keys (digit == d1)
  uint32_t wavesum[4];
  uint32_t digit;
  uint32_t rem;
  uint32_t cnt;                    // candidate count
};

// Suffix-scan + winner pick shared by all phases. hb[] are this thread's bin
// counts over bins [tid*BPT, tid*BPT+BPT). S(b) = #candidates with digit >= b.
// Winner: S(b) >= rem && S(b+1) < rem (unique). Updates rem to rank in bin.
template <int BPT>
__device__ __forceinline__ uint32_t pick_winner(Shared& sh, const uint32_t (&hb)[BPT],
                                                uint32_t& rem, int tid, int lane, int wave) {
  uint32_t L = 0;
#pragma unroll
  for (int j = 0; j < BPT; ++j) L += hb[j];

  // Wave-level inclusive suffix scan of L (no barriers).
  uint32_t suf = L;
#pragma unroll
  for (int off = 1; off < 64; off <<= 1) {
    uint32_t o = __shfl_down(suf, off, 64);
    suf += (lane + off < 64) ? o : 0u;
  }
  if (lane == 0) sh.wavesum[wave] = suf;   // wave total
  __syncthreads();
  uint32_t addw = 0;
#pragma unroll
  for (int w = 0; w < 4; ++w) addw += (w > wave) ? sh.wavesum[w] : 0u;
  suf += addw;  // suffix count starting at this thread's first bin

  uint32_t s = suf - L;                    // S at bin (tid+1)*BPT
#pragma unroll
  for (int j = BPT - 1; j >= 0; --j) {
    uint32_t snext = s;                    // S(bin+1)
    s += hb[j];                            // S(bin)
    if (s >= rem && snext < rem) {
      sh.digit = (uint32_t)(tid * BPT + j);
      sh.rem = rem - snext;
    }
  }
  __syncthreads();
  uint32_t d = sh.digit;
  rem = sh.rem;
  // No trailing barrier needed: the next stage's first barrier (after
  // zeroing / scatter) orders these reads before any write to
  // digit/rem/wavesum (zeroing touches hist[] only; compact touches
  // cand[]/cnt only).
  return d;
}

// Phase 1: 11-bit digit (bits 30..20), 2048 bins, u16-packed, 2 copies.
// Packing: bin b -> word (b & 1023), halfword (b >> 10); the two halves of a
// word differ by 128 in the exponent field so they are never both hot, and
// per-copy per-half counts <= 4096 < 2^16. Also zeroes sh.cnt for compact.
__device__ __forceinline__ uint32_t phase1(Shared& sh, const uint4 (&v)[VPT],
                                           uint32_t& rem, int tid, int lane, int wave) {
  uint4* hz = (uint4*)sh.hist;
  constexpr int ZW4 = (C1 * S1) / 4;       // 516
  for (int i = tid; i < ZW4; i += TPB) hz[i] = make_uint4(0u, 0u, 0u, 0u);
  if (tid == 0) sh.cnt = 0;
  __syncthreads();

  uint32_t* h = &sh.hist[(wave >> 1) * S1];
#pragma unroll
  for (int i = 0; i < VPT; ++i) {
    uint32_t a[4] = {v[i].x, v[i].y, v[i].z, v[i].w};
#pragma unroll
    for (int j = 0; j < 4; ++j) {
      uint32_t d = (a[j] & 0x7fffffffu) >> 20;          // 11-bit digit
      atomicAdd(&h[d & (W1 - 1)], 1u << ((d >> 10) << 4));
    }
  }
  __syncthreads();

  // Combine copies; thread owns bins [tid*8, tid*8+8), all in one halfword.
  constexpr int BPT = 2048 / TPB;          // 8
  uint32_t hb[BPT];
#pragma unroll
  for (int j = 0; j < BPT; ++j) hb[j] = 0;
  const int wbase = (tid & 127) * BPT;     // word base within a copy
  const int shift = (tid >> 7) << 4;       // low half (tid<128) / high half
#pragma unroll
  for (int c = 0; c < C1; ++c) {
    const uint4* hp = (const uint4*)&sh.hist[c * S1 + wbase];
#pragma unroll
    for (int q = 0; q < BPT / 4; ++q) {
      uint4 t = hp[q];
      hb[4 * q + 0] += (t.x >> shift) & 0xffffu;
      hb[4 * q + 1] += (t.y >> shift) & 0xffffu;
      hb[4 * q + 2] += (t.z >> shift) & 0xffffu;
      hb[4 * q + 3] += (t.w >> shift) & 0xffffu;
    }
  }
  return pick_winner<BPT>(sh, hb, rem, tid, lane, wave);
}

// Phases 2/3 over the compacted candidate list (all keys have digit1 == d1).
// Phase 2 (FILTER=false): digit = bits 19..10, no predicate needed.
// Phase 3 (FILTER=true):  digit = bits  9..0, keep only digit2 == d2match.
template <bool FILTER>
__device__ __forceinline__ uint32_t phase_list(Shared& sh, int dshift,
                                               uint32_t d2match, uint32_t total,
                                               uint32_t& rem, int tid, int lane, int wave) {
  uint4* hz = (uint4*)sh.hist;
  constexpr int ZW4 = S2 / 4;              // 258
  for (int i = tid; i < ZW4; i += TPB) hz[i] = make_uint4(0u, 0u, 0u, 0u);
  __syncthreads();

  for (uint32_t p = tid; p < total; p += TPB) {    // ~1 iteration (total ~200)
    uint32_t key = sh.cand[p];
    if (!FILTER || (((key >> 10) & 1023u) == d2match))
      atomicAdd(&sh.hist[(key >> dshift) & (B2 - 1)], 1u);
  }
  __syncthreads();

  constexpr int BPT = B2 / TPB;            // 4
  uint32_t hb[BPT];
  const uint4 t = *(const uint4*)&sh.hist[tid * BPT];
  hb[0] = t.x; hb[1] = t.y; hb[2] = t.z; hb[3] = t.w;
  return pick_winner<BPT>(sh, hb, rem, tid, lane, wave);
}

// Fallback full-scan phases 2/3 (only if the d1 bin overflows CAND_MAX --
// impossible for this input, kept for exactness on any input).
__device__ __forceinline__ uint32_t phase23_full(Shared& sh, const uint4 (&v)[VPT],
                                                 int dshift, int cshift, uint32_t cprefix,
                                                 uint32_t& rem, int tid, int lane, int wave) {
  uint4* hz = (uint4*)sh.hist;
  constexpr int ZW4 = S2 / 4;
  for (int i = tid; i < ZW4; i += TPB) hz[i] = make_uint4(0u, 0u, 0u, 0u);
  __syncthreads();

#pragma unroll
  for (int i = 0; i < VPT; ++i) {
    uint32_t a[4] = {v[i].x, v[i].y, v[i].z, v[i].w};
#pragma unroll
    for (int j = 0; j < 4; ++j) {
      uint32_t key = a[j] & 0x7fffffffu;
      if ((key >> cshift) == cprefix)
        atomicAdd(&sh.hist[(key >> dshift) & (B2 - 1)], 1u);
    }
  }
  __syncthreads();

  constexpr int BPT = B2 / TPB;
  uint32_t hb[BPT];
  const uint4 t = *(const uint4*)&sh.hist[tid * BPT];
  hb[0] = t.x; hb[1] = t.y; hb[2] = t.z; hb[3] = t.w;
  return pick_winner<BPT>(sh, hb, rem, tid, lane, wave);
}

__global__ __launch_bounds__(TPB, 4) void topk_row_kernel(const float* __restrict__ x,
                                                          float* __restrict__ out,
                                                          int K) {
  __shared__ Shared sh;
  const int row  = blockIdx.x;
  const int tid  = threadIdx.x;
  const int lane = tid & 63;
  const int wave = tid >> 6;

  const uint4* xr = (const uint4*)(x) + (size_t)row * V4;
  uint4 v[VPT];
#pragma unroll
  for (int i = 0; i < VPT; ++i) v[i] = xr[tid + i * TPB];

  // Pin the row in the register file (forbids remat; AGPR parking proven
  // cheap in R4-R6). Zero instructions.
#pragma unroll
  for (int i = 0; i < VPT; ++i)
    asm volatile("" : "+v"(v[i].x), "+v"(v[i].y), "+v"(v[i].z), "+v"(v[i].w));

  uint32_t rem = (uint32_t)K;
  uint32_t d1 = phase1(sh, v, rem, tid, lane, wave);

  // Compact the d1 bin: scatter matching keys to the LDS list. ~200 matches
  // total (~0.8/thread). cnt counts ALL matches even past CAND_MAX so the
  // overflow test is exact; writes are guarded.
#pragma unroll
  for (int i = 0; i < VPT; ++i) {
    uint32_t a[4] = {v[i].x, v[i].y, v[i].z, v[i].w};
#pragma unroll
    for (int j = 0; j < 4; ++j) {
      uint32_t key = a[j] & 0x7fffffffu;
      if ((key >> 20) == d1) {
        uint32_t p = atomicAdd(&sh.cnt, 1u);
        if (p < (uint32_t)CAND_MAX) sh.cand[p] = key;
      }
    }
  }
  __syncthreads();
  const uint32_t total = sh.cnt;           // uniform

  uint32_t d2, d3;
  if (total <= (uint32_t)CAND_MAX) {
    d2 = phase_list<false>(sh, 10, 0, total, rem, tid, lane, wave);
    d3 = phase_list<true>(sh, 0, d2, total, rem, tid, lane, wave);
  } else {
    d2 = phase23_full(sh, v, 10, 20, d1, rem, tid, lane, wave);
    d3 = phase23_full(sh, v, 0, 10, (d1 << 10) | d2, rem, tid, lane, wave);
  }

  const uint32_t thr = (d1 << 20) | (d2 << 10) | d3;  // exact K-th largest |x| bits

  uint4* outr = (uint4*)(out) + (size_t)row * V4;
#pragma unroll
  for (int i = 0; i < VPT; ++i) {
    uint4 o = v[i];
    o.x = ((o.x & 0x7fffffffu) >= thr) ? o.x : 0u;
    o.y = ((o.y & 0x7fffffffu) >= thr) ? o.y : 0u;
    o.z = ((o.z & 0x7fffffffu) >= thr) ? o.z : 0u;
    o.w = ((o.w & 0x7fffffffu) >= thr) ? o.w : 0u;
    outr[tid + i * TPB] = o;
  }
}

extern "C" void kernel_launch(void* const* d_in, const int* in_sizes, int n_in,
                              void* d_out, int out_size, void* d_ws, size_t ws_size,
                              hipStream_t stream) {
  (void)n_in; (void)out_size; (void)d_ws; (void)ws_size;
  const float* x = (const float*)d_in[0];
  float* out = (float*)d_out;
  const int rows = in_sizes[0] / NCOLS;
  const int K = (int)(0.1 * NCOLS + 0.5);  // round(819.2) = 819
  topk_row_kernel<<<rows, TPB, 0, stream>>>(x, out, K);
}

// Round 10
// 230.321 us; speedup vs baseline: 1.0633x; 1.0134x over previous
//
#include <hip/hip_runtime.h>
#include <stdint.h>

// Per-row top-K magnitude masking, exact.
// x: (4096 rows, 8192 cols) fp32. K = 819. One 256-thread block per row, row
// held in registers (8 x uint4 / thread). Exact radix select on the 31-bit
// abs bit pattern in 3 phases: 11 bits (2048 bins), 10 bits, 10 bits.
//
// This rev: 8-WAY COPY DILUTION OF SAME-ADDRESS LDS-ATOMIC RMW.
// R0-R9 forensics: ten structures (occupancy 17-64%, zero-barrier,
// streamed, pair-fused, compacted) all land at 83-97 us with no pipe >30%.
// R9 was the tell: deleting ~40% of VALU work but adding ~200 atomics to a
// SINGLE LDS address made it SLOWER -> same-address LDS RMW serialization
// (~10-30 cyc per colliding lane, NOT counted by SQ_LDS_BANK_CONFLICT) is
// the hidden invariant cost. All revs do 8192 atomics/row into Gaussian-hot
// bins (hottest ~5% -> intra-wave max multiplicity ~4-6) = ~4-8K cyc/row.
// Fix: phase-1 histogram now has 8 copies, one per 8-LANE GROUP (was: 1 per
// wave-pair) -> same-address collisions confined to 8 lanes, expected max
// multiplicity ~1.5. Copies are u16-packed (bin b -> word b&1023, half
// b>>10; counts per copy <= 1024 < 2^16); combine sums the 8 copies' words
// as packed u32 (halves can't carry: per-word half-sums <= 8192 < 2^16).
// Phases 2/3 = R1/R6's proven full-scan (R9's compact deleted).

constexpr int NCOLS = 8192;
constexpr int TPB   = 256;
constexpr int V4    = NCOLS / 4;   // 2048 uint4 per row
constexpr int VPT   = V4 / TPB;    // 8 uint4 per thread

constexpr int PAD = 8;             // words between histogram copies (bank shift)
constexpr int W1  = 1024;          // phase-1 words per copy (2048 bins, u16-packed)
constexpr int S1  = W1 + PAD;      // 1032
constexpr int C1  = 8;             // phase-1 copies: one per 8-lane group
constexpr int B2  = 1024;          // phase-2/3 bins (u32, single copy)
constexpr int S2  = B2 + PAD;      // 1032
constexpr int HW  = C1 * S1;       // 8256 words = 33 KB (>= S2)

struct Shared {
  uint32_t hist[HW];
  uint32_t wavesum[4];
  uint32_t digit;
  uint32_t rem;
};

// Suffix-scan + winner pick shared by all phases. hb[] are this thread's bin
// counts over bins [tid*BPT, tid*BPT+BPT). S(b) = #candidates with digit >= b.
// Winner: S(b) >= rem && S(b+1) < rem (unique). Updates rem to rank in bin.
template <int BPT>
__device__ __forceinline__ uint32_t pick_winner(Shared& sh, const uint32_t (&hb)[BPT],
                                                uint32_t& rem, int tid, int lane, int wave) {
  uint32_t L = 0;
#pragma unroll
  for (int j = 0; j < BPT; ++j) L += hb[j];

  // Wave-level inclusive suffix scan of L (no barriers).
  uint32_t suf = L;
#pragma unroll
  for (int off = 1; off < 64; off <<= 1) {
    uint32_t o = __shfl_down(suf, off, 64);
    suf += (lane + off < 64) ? o : 0u;
  }
  if (lane == 0) sh.wavesum[wave] = suf;   // wave total
  __syncthreads();
  uint32_t addw = 0;
#pragma unroll
  for (int w = 0; w < 4; ++w) addw += (w > wave) ? sh.wavesum[w] : 0u;
  suf += addw;  // suffix count starting at this thread's first bin

  uint32_t s = suf - L;                    // S at bin (tid+1)*BPT
#pragma unroll
  for (int j = BPT - 1; j >= 0; --j) {
    uint32_t snext = s;                    // S(bin+1)
    s += hb[j];                            // S(bin)
    if (s >= rem && snext < rem) {
      sh.digit = (uint32_t)(tid * BPT + j);
      sh.rem = rem - snext;
    }
  }
  __syncthreads();
  uint32_t d = sh.digit;
  rem = sh.rem;
  // No trailing barrier needed: next phase's first barrier (after zeroing)
  // orders these reads before any write to sh.digit/sh.rem/wavesum, and the
  // zeroing only touches hist[], whose reads completed before the wavesum
  // barrier above.
  return d;
}

// Phase 1: 11-bit digit (bits 30..20), 2048 bins, u16-packed, 8 copies,
// copy = (tid>>3)&7 -> same-address RMW collisions confined to 8 lanes.
__device__ __forceinline__ uint32_t phase1(Shared& sh, const uint4 (&v)[VPT],
                                           uint32_t& rem, int tid, int lane, int wave) {
  uint4* hz = (uint4*)sh.hist;
  constexpr int ZW4 = (C1 * S1) / 4;       // 2064
  for (int i = tid; i < ZW4; i += TPB) hz[i] = make_uint4(0u, 0u, 0u, 0u);
  __syncthreads();

  uint32_t* h = &sh.hist[((tid >> 3) & 7) * S1];
#pragma unroll
  for (int i = 0; i < VPT; ++i) {
    uint32_t a[4] = {v[i].x, v[i].y, v[i].z, v[i].w};
#pragma unroll
    for (int j = 0; j < 4; ++j) {
      uint32_t d = (a[j] & 0x7fffffffu) >> 20;          // 11-bit digit
      atomicAdd(&h[d & (W1 - 1)], 1u << ((d >> 10) << 4));
    }
  }
  __syncthreads();

  // Combine copies. Thread owns bins [tid*8, tid*8+8), all in one halfword
  // of words wbase..wbase+8. Sum the 8 copies' words as packed u32 first
  // (halves can't carry into each other: half-sums <= 8192 < 2^16), then
  // extract this thread's half once.
  constexpr int BPT = 2048 / TPB;          // 8
  const int wbase = (tid & 127) * BPT;     // word base within a copy
  const int shift = (tid >> 7) << 4;       // low half (tid<128) / high half
  uint32_t ws[BPT];
#pragma unroll
  for (int j = 0; j < BPT; ++j) ws[j] = 0;
#pragma unroll
  for (int c = 0; c < C1; ++c) {
    const uint4* hp = (const uint4*)&sh.hist[c * S1 + wbase];
    uint4 t0 = hp[0], t1 = hp[1];
    ws[0] += t0.x; ws[1] += t0.y; ws[2] += t0.z; ws[3] += t0.w;
    ws[4] += t1.x; ws[5] += t1.y; ws[6] += t1.z; ws[7] += t1.w;
  }
  uint32_t hb[BPT];
#pragma unroll
  for (int j = 0; j < BPT; ++j) hb[j] = (ws[j] >> shift) & 0xffffu;
  return pick_winner<BPT>(sh, hb, rem, tid, lane, wave);
}

// Phases 2/3: 10-bit digit, 1024 u32 bins, single copy. Candidate streams
// are sparse (~819 then ~80 of 8192) -> same-address pressure is tiny.
__device__ __forceinline__ uint32_t phase23(Shared& sh, const uint4 (&v)[VPT],
                                            int dshift, int cshift, uint32_t cprefix,
                                            uint32_t& rem, int tid, int lane, int wave) {
  uint4* hz = (uint4*)sh.hist;
  constexpr int ZW4 = S2 / 4;              // 258
  for (int i = tid; i < ZW4; i += TPB) hz[i] = make_uint4(0u, 0u, 0u, 0u);
  __syncthreads();

#pragma unroll
  for (int i = 0; i < VPT; ++i) {
    uint32_t a[4] = {v[i].x, v[i].y, v[i].z, v[i].w};
#pragma unroll
    for (int j = 0; j < 4; ++j) {
      uint32_t key = a[j] & 0x7fffffffu;
      if ((key >> cshift) == cprefix)
        atomicAdd(&sh.hist[(key >> dshift) & (B2 - 1)], 1u);
    }
  }
  __syncthreads();

  constexpr int BPT = B2 / TPB;            // 4
  uint32_t hb[BPT];
  const uint4 t = *(const uint4*)&sh.hist[tid * BPT];
  hb[0] = t.x; hb[1] = t.y; hb[2] = t.z; hb[3] = t.w;
  return pick_winner<BPT>(sh, hb, rem, tid, lane, wave);
}

__global__ __launch_bounds__(TPB, 4) void topk_row_kernel(const float* __restrict__ x,
                                                          float* __restrict__ out,
                                                          int K) {
  __shared__ Shared sh;
  const int row  = blockIdx.x;
  const int tid  = threadIdx.x;
  const int lane = tid & 63;
  const int wave = tid >> 6;

  const uint4* xr = (const uint4*)(x) + (size_t)row * V4;
  uint4 v[VPT];
#pragma unroll
  for (int i = 0; i < VPT; ++i) v[i] = xr[tid + i * TPB];

  // Pin the row in the register file (forbids remat; AGPR parking proven
  // cheap in R4-R6). Zero instructions.
#pragma unroll
  for (int i = 0; i < VPT; ++i)
    asm volatile("" : "+v"(v[i].x), "+v"(v[i].y), "+v"(v[i].z), "+v"(v[i].w));

  uint32_t rem = (uint32_t)K;
  uint32_t d1 = phase1(sh, v, rem, tid, lane, wave);
  uint32_t d2 = phase23(sh, v, 10, 20, d1, rem, tid, lane, wave);
  uint32_t d3 = phase23(sh, v,  0, 10, (d1 << 10) | d2, rem, tid, lane, wave);

  const uint32_t thr = (d1 << 20) | (d2 << 10) | d3;  // exact K-th largest |x| bits

  uint4* outr = (uint4*)(out) + (size_t)row * V4;
#pragma unroll
  for (int i = 0; i < VPT; ++i) {
    uint4 o = v[i];
    o.x = ((o.x & 0x7fffffffu) >= thr) ? o.x : 0u;
    o.y = ((o.y & 0x7fffffffu) >= thr) ? o.y : 0u;
    o.z = ((o.z & 0x7fffffffu) >= thr) ? o.z : 0u;
    o.w = ((o.w & 0x7fffffffu) >= thr) ? o.w : 0u;
    outr[tid + i * TPB] = o;
  }
}

extern "C" void kernel_launch(void* const* d_in, const int* in_sizes, int n_in,
                              void* d_out, int out_size, void* d_ws, size_t ws_size,
                              hipStream_t stream) {
  (void)n_in; (void)out_size; (void)d_ws; (void)ws_size;
  const float* x = (const float*)d_in[0];
  float* out = (float*)d_out;
  const int rows = in_sizes[0] / NCOLS;
  const int K = (int)(0.1 * NCOLS + 0.5);  // round(819.2) = 819
  topk_row_kernel<<<rows, TPB, 0, stream>>>(x, out, K);
}